// Round 6
// baseline (175.538 us; speedup 1.0000x reference)
//
#include <hip/hip_runtime.h>
#include <math.h>

#define MM 64
#define NA 24
#define NP 276
#define NT 6000
#define NTP 6016   // padded t-stride for transposed arrays
#define QC 0.22360679774997896f
#define EXPC 0.01666666666666667f  // 5/(3*sig^2), sig=10

// ws layout (float offsets)
#define OFF_XST  0                 // xsT[p][m] 276*64
#define OFF_UU   17664             // 64
#define OFF_VV   17728             // 6000
#define OFF_C1   23728             // 6000
#define OFF_ES   29728             // 64     (zeroed)
#define OFF_SW   29792             // 64     (zeroed)
#define OFF_SH   29856             // 8 shadows * 2 * [276][64] (zeroed)
#define OFF_WT   312480            // w  [t][m] 6000*64
#define OFF_ET   696480            // e1 [t][m] 6000*64
#define OFF_XJT  1080480           // (xt,Ja) interleaved transposed [276][NTP][2]
#define ZTOT     282752            // floats to zero at OFF_ES
// total ws: 1080480 + 276*6016*2 = 4,401,312 floats = 17.6 MB

__device__ __forceinline__ float f4c(const float4& v, int i) {
  return i == 0 ? v.x : i == 1 ? v.y : i == 2 ? v.z : v.w;
}

// ---------- kernel 1: zero accum + xs-prep (xsT, uu) + fused transpose/stats ----------
// blocks 0..63: xsT + uu for m = blockIdx.x
// blocks 64..251: 32-t strip: row stats (vv, c1) + tiled transpose into xjT
__global__ __launch_bounds__(256) void k_pre(const float* __restrict__ Rs,
                                             const float* __restrict__ xt,
                                             const float* __restrict__ Ja,
                                             float* __restrict__ ws) {
  const int tid = threadIdx.x;
  for (int z = blockIdx.x * 256 + tid; z < ZTOT; z += gridDim.x * 256)
    ws[OFF_ES + z] = 0.f;

  if (blockIdx.x < MM) {
    const int m = blockIdx.x;
    __shared__ float sR[NA * 3];
    __shared__ float sAcc[4];
    if (tid < NA * 3) sR[tid] = Rs[m * NA * 3 + tid];
    __syncthreads();
    float acc = 0.f;
    for (int p = tid; p < NP; p += 256) {
      int i = (int)((1.0f + sqrtf(1.0f + 8.0f * (float)p)) * 0.5f);
      while (i * (i - 1) / 2 > p) i--;
      while ((i + 1) * i / 2 <= p) i++;
      int j = p - i * (i - 1) / 2;
      float dx = sR[i * 3 + 0] - sR[j * 3 + 0];
      float dy = sR[i * 3 + 1] - sR[j * 3 + 1];
      float dz = sR[i * 3 + 2] - sR[j * 3 + 2];
      float u = 1.0f / sqrtf(dx * dx + dy * dy + dz * dz);
      ws[OFF_XST + p * 64 + m] = u;
      acc += u * u;
    }
    for (int off = 32; off; off >>= 1) acc += __shfl_down(acc, off);
    if ((tid & 63) == 0) sAcc[tid >> 6] = acc;
    __syncthreads();
    if (tid == 0) ws[OFF_UU + m] = sAcc[0] + sAcc[1] + sAcc[2] + sAcc[3];
  } else {
    const int t0 = (blockIdx.x - MM) * 32;
    const int tl = tid >> 5;   // 0..7
    const int pl = tid & 31;
    __shared__ float lx[32][33];
    __shared__ float lj[32][33];
    float vvp[4] = {0.f, 0.f, 0.f, 0.f};
    float c1p[4] = {0.f, 0.f, 0.f, 0.f};
    for (int c9 = 0; c9 < 9; c9++) {
      const int p = c9 * 32 + pl;
      const bool pok = (p < NP);
      __syncthreads();
#pragma unroll
      for (int tt = 0; tt < 4; tt++) {
        const int t = t0 + tl * 4 + tt;
        float v = 0.f, j = 0.f;
        if (pok && t < NT) {
          v = xt[(size_t)t * NP + p];
          j = Ja[(size_t)t * NP + p];
        }
        vvp[tt] += v * v;
        c1p[tt] += v * j;
        lx[pl][tl * 4 + tt] = v;
        lj[pl][tl * 4 + tt] = j;
      }
      __syncthreads();
      const int tlw = tid & 31;
      const int plw = tid >> 5;
#pragma unroll
      for (int pp = 0; pp < 4; pp++) {
        const int pLoc = plw * 4 + pp;
        const int pOut = c9 * 32 + pLoc;
        if (pOut < NP) {
          *(float2*)(ws + OFF_XJT + ((size_t)pOut * NTP + t0 + tlw) * 2) =
              make_float2(lx[pLoc][tlw], lj[pLoc][tlw]);
        }
      }
    }
#pragma unroll
    for (int off = 16; off; off >>= 1) {
#pragma unroll
      for (int tt = 0; tt < 4; tt++) {
        vvp[tt] += __shfl_down(vvp[tt], off, 32);
        c1p[tt] += __shfl_down(c1p[tt], off, 32);
      }
    }
    if (pl == 0) {
#pragma unroll
      for (int tt = 0; tt < 4; tt++) {
        const int t = t0 + tl * 4 + tt;
        if (t < NT) { ws[OFF_VV + t] = vvp[tt]; ws[OFF_C1 + t] = c1p[tt]; }
      }
    }
  }
}

// ---------- kernel 2: GEMM1 + elementwise, scalar-broadcast matvec style ----------
// lane = t (coalesced xjT stream), block 64, grid (94 t-tiles x 8 m-octets).
// Per p: 1 coalesced b64 (xjT) + 2 wave-uniform s_load x4 (xsT) + 16 FMA.
// No LDS, no barriers. Writes wT/e1T [t][m]; atomics for Es/sumw.
__global__ __launch_bounds__(64) void k_g1(float* __restrict__ ws) {
  const int lane = threadIdx.x;
  const int t = blockIdx.x * 64 + lane;       // < 6016; pad region holds zeros
  const int m0 = blockIdx.y * 8;
  const float* __restrict__ xj = ws + OFF_XJT + (size_t)t * 2;
  const float* __restrict__ xs = ws + OFF_XST + m0;   // wave-uniform
  float av[8] = {0.f,0.f,0.f,0.f,0.f,0.f,0.f,0.f};
  float aj[8] = {0.f,0.f,0.f,0.f,0.f,0.f,0.f,0.f};
#pragma unroll 4
  for (int p = 0; p < NP; p++) {
    const float2 x = *(const float2*)(xj + (size_t)p * (NTP * 2));
    const float4 a0 = *(const float4*)(xs + p * 64);      // uniform -> SGPR
    const float4 a1 = *(const float4*)(xs + p * 64 + 4);  // uniform -> SGPR
    av[0] = fmaf(a0.x, x.x, av[0]); aj[0] = fmaf(a0.x, x.y, aj[0]);
    av[1] = fmaf(a0.y, x.x, av[1]); aj[1] = fmaf(a0.y, x.y, aj[1]);
    av[2] = fmaf(a0.z, x.x, av[2]); aj[2] = fmaf(a0.z, x.y, aj[2]);
    av[3] = fmaf(a0.w, x.x, av[3]); aj[3] = fmaf(a0.w, x.y, aj[3]);
    av[4] = fmaf(a1.x, x.x, av[4]); aj[4] = fmaf(a1.x, x.y, aj[4]);
    av[5] = fmaf(a1.y, x.x, av[5]); aj[5] = fmaf(a1.y, x.y, aj[5]);
    av[6] = fmaf(a1.z, x.x, av[6]); aj[6] = fmaf(a1.z, x.y, aj[6]);
    av[7] = fmaf(a1.w, x.x, av[7]); aj[7] = fmaf(a1.w, x.y, aj[7]);
  }
  const bool tok = (t < NT);
  const float vvt = tok ? ws[OFF_VV + t] : 0.f;
  const float c1t = tok ? ws[OFF_C1 + t] : 0.f;
  float wv[8], ev[8], es8[8], sw8[8];
#pragma unroll
  for (int i = 0; i < 8; i++) {
    const float uum = ws[OFF_UU + m0 + i];  // uniform
    float d2 = fmaxf(uum - 2.f * av[i] + vvt, 0.f);
    float xd = QC * sqrtf(d2);
    float dv = QC * (aj[i] - c1t);
    float ex = EXPC * __expf(-xd);
    float e1v = ex * (1.f + xd);
    float w_ = ex * dv;
    if (!tok) { e1v = 0.f; w_ = 0.f; dv = 0.f; }
    wv[i] = w_; ev[i] = e1v;
    es8[i] = e1v * dv;
    sw8[i] = w_;
  }
  if (tok) {
    float* wp = ws + OFF_WT + (size_t)t * 64 + m0;
    float* ep = ws + OFF_ET + (size_t)t * 64 + m0;
    *(float4*)wp       = make_float4(wv[0], wv[1], wv[2], wv[3]);
    *(float4*)(wp + 4) = make_float4(wv[4], wv[5], wv[6], wv[7]);
    *(float4*)ep       = make_float4(ev[0], ev[1], ev[2], ev[3]);
    *(float4*)(ep + 4) = make_float4(ev[4], ev[5], ev[6], ev[7]);
  }
#pragma unroll
  for (int off = 32; off; off >>= 1) {
#pragma unroll
    for (int i = 0; i < 8; i++) {
      es8[i] += __shfl_down(es8[i], off);
      sw8[i] += __shfl_down(sw8[i], off);
    }
  }
  if (lane == 0) {
#pragma unroll
    for (int i = 0; i < 8; i++) {
      atomicAdd(ws + OFF_ES + m0 + i, es8[i]);
      atomicAdd(ws + OFF_SW + m0 + i, sw8[i]);
    }
  }
}

// ---------- kernel 3: GEMM2 partials: shadow[s][0] += w@xt, shadow[s][1] += e1@Ja ----------
#define G2_KC 125
__global__ __launch_bounds__(256) void k_g2(const float* __restrict__ xt,
                                            const float* __restrict__ Ja,
                                            float* __restrict__ ws) {
  __shared__ __align__(16) float Bsv[G2_KC][16];
  __shared__ __align__(16) float Bsj[G2_KC][16];
  const int tid = threadIdx.x;
  const int p0 = blockIdx.x * 16;
  const int k0 = blockIdx.y * G2_KC;
  const int validp = (NP - p0 < 16) ? (NP - p0) : 16;

  for (int idx = tid; idx < G2_KC * 8; idx += 256) {
    const int q = idx & 3;
    const int mat = (idx >> 2) & 1;
    const int row = idx >> 3;
    float4 val = make_float4(0.f, 0.f, 0.f, 0.f);
    if (q * 4 < validp)
      val = *(const float4*)((mat ? Ja : xt) + (size_t)(k0 + row) * NP + p0 + q * 4);
    *(float4*)&(mat ? Bsj : Bsv)[row][q * 4] = val;
  }
  __syncthreads();

  const int m = tid & 63;
  const int pg = tid >> 6;  // 0..3
  const float* wtp = ws + OFF_WT + (size_t)k0 * 64 + m;
  const float* etp = ws + OFF_ET + (size_t)k0 * 64 + m;
  float acc1[4] = {0.f, 0.f, 0.f, 0.f};
  float acc2[4] = {0.f, 0.f, 0.f, 0.f};

#pragma unroll 5
  for (int k = 0; k < G2_KC; k++) {
    const float aw = wtp[k * 64];
    const float ae = etp[k * 64];
    const float4 bv = *(const float4*)&Bsv[k][pg * 4];
    const float4 bj = *(const float4*)&Bsj[k][pg * 4];
    acc1[0] = fmaf(aw, bv.x, acc1[0]); acc2[0] = fmaf(ae, bj.x, acc2[0]);
    acc1[1] = fmaf(aw, bv.y, acc1[1]); acc2[1] = fmaf(ae, bj.y, acc2[1]);
    acc1[2] = fmaf(aw, bv.z, acc1[2]); acc2[2] = fmaf(ae, bj.z, acc2[2]);
    acc1[3] = fmaf(aw, bv.w, acc1[3]); acc2[3] = fmaf(ae, bj.w, acc2[3]);
  }

  const int sh = blockIdx.y & 7;
  float* base1 = ws + OFF_SH + (size_t)(sh * 2 + 0) * NP * 64;
  float* base2 = ws + OFF_SH + (size_t)(sh * 2 + 1) * NP * 64;
#pragma unroll
  for (int j = 0; j < 4; j++) {
    const int p = p0 + pg * 4 + j;
    if (p < NP && pg * 4 + j < validp) {
      atomicAdd(base1 + (size_t)p * 64 + m, acc1[j]);
      atomicAdd(base2 + (size_t)p * 64 + m, acc2[j]);
    }
  }
}

// ---------- kernel 4: finalize (reduce shadows, force gather, Es) ----------
__global__ __launch_bounds__(320) void k_final(const float* __restrict__ Rs,
                                               const float* __restrict__ ws,
                                               float* __restrict__ out) {
  const int m = blockIdx.x;
  const int tid = threadIdx.x;
  __shared__ float fx[NP];
  __shared__ float sR[NA * 3];
  if (tid < NA * 3) sR[tid] = Rs[m * NA * 3 + tid];
  const float sw = ws[OFF_SW + m];
  for (int p = tid; p < NP; p += 320) {
    float f1p = 0.f, f2 = 0.f;
#pragma unroll
    for (int s = 0; s < 8; s++) {
      f1p += ws[OFF_SH + ((size_t)(s * 2 + 0) * NP + p) * 64 + m];
      f2  += ws[OFF_SH + ((size_t)(s * 2 + 1) * NP + p) * 64 + m];
    }
    const float u = ws[OFF_XST + p * 64 + m];
    const float F1 = QC * (u * sw - f1p);
    fx[p] = (F1 - f2) * u * u * u;
  }
  __syncthreads();
  if (tid == 0) out[m] = ws[OFF_ES + m] / QC;  // *STD + C, STD=1, C=0
  if (tid < NA * 3) {
    const int a = tid / 3, cc = tid % 3;
    const float ra = sR[a * 3 + cc];
    float acc = 0.f;
    for (int b = 0; b < NA; b++) {
      if (b == a) continue;
      const int i = a > b ? a : b, j = a > b ? b : a;
      const int p = i * (i - 1) / 2 + j;
      acc += (sR[b * 3 + cc] - ra) * fx[p];
    }
    out[MM + m * NA * 3 + tid] = acc;
  }
}

extern "C" void kernel_launch(void* const* d_in, const int* in_sizes, int n_in,
                              void* d_out, int out_size, void* d_ws, size_t ws_size,
                              hipStream_t stream) {
  const float* Rs = (const float*)d_in[0];
  const float* xt = (const float*)d_in[1];
  const float* Ja = (const float*)d_in[2];
  float* out = (float*)d_out;
  float* ws = (float*)d_ws;

  k_pre<<<MM + 188, 256, 0, stream>>>(Rs, xt, Ja, ws);
  k_g1<<<dim3(94, 8), 64, 0, stream>>>(ws);
  k_g2<<<dim3(18, NT / G2_KC), 256, 0, stream>>>(xt, Ja, ws);
  k_final<<<MM, 320, 0, stream>>>(Rs, ws, out);
}

// Round 7
// 144.577 us; speedup vs baseline: 1.2142x; 1.2142x over previous
//
#include <hip/hip_runtime.h>
#include <math.h>

#define MM 64
#define NA 24
#define NP 276
#define NT 6000
#define NTP 6016   // padded t-rows for wT/eT (zero tail)
#define QC 0.22360679774997896f
#define EXPC 0.01666666666666667f  // 5/(3*sig^2), sig=10

// ws layout (float offsets)
#define OFF_XS   0                 // xs[m][p] 64*276
#define OFF_UU   17664             // 64
#define OFF_VV   17728             // 6000
#define OFF_C1   23728             // 6000
#define OFF_ES   29728             // 64     (zeroed)
#define OFF_SW   29792             // 64     (zeroed)
#define OFF_SH   29856             // 8 shadows * 2 * [276][64] (zeroed)
#define OFF_WT   312480            // w  [t][m] NTP*64 (tail rows zeroed)
#define OFF_ET   697504            // e1 [t][m] NTP*64 (tail rows zeroed)
#define ZTOT     282752            // floats to zero at OFF_ES
// total: 697504 + 385024 = 1,082,528 floats = 4.33 MB

__device__ __forceinline__ float f4c(const float4& v, int i) {
  return i == 0 ? v.x : i == 1 ? v.y : i == 2 ? v.z : v.w;
}

// ---------- kernel 1: prep (xs, uu) + stats (vv, c1) + zero accum & tails ----------
__global__ __launch_bounds__(256) void k_pre(const float* __restrict__ Rs,
                                             const float* __restrict__ xt,
                                             const float* __restrict__ Ja,
                                             float* __restrict__ ws) {
  const int tid = threadIdx.x;
  for (int z = blockIdx.x * 256 + tid; z < ZTOT; z += gridDim.x * 256)
    ws[OFF_ES + z] = 0.f;
  for (int z = blockIdx.x * 256 + tid; z < 2048; z += gridDim.x * 256) {
    if (z < 1024) ws[OFF_WT + 384000 + z] = 0.f;
    else         ws[OFF_ET + 384000 + (z - 1024)] = 0.f;
  }

  if (blockIdx.x < MM) {
    const int m = blockIdx.x;
    __shared__ float sR[NA * 3];
    __shared__ float sAcc[4];
    if (tid < NA * 3) sR[tid] = Rs[m * NA * 3 + tid];
    __syncthreads();
    float acc = 0.f;
    for (int p = tid; p < NP; p += 256) {
      int i = (int)((1.0f + sqrtf(1.0f + 8.0f * (float)p)) * 0.5f);
      while (i * (i - 1) / 2 > p) i--;
      while ((i + 1) * i / 2 <= p) i++;
      int j = p - i * (i - 1) / 2;
      float dx = sR[i * 3 + 0] - sR[j * 3 + 0];
      float dy = sR[i * 3 + 1] - sR[j * 3 + 1];
      float dz = sR[i * 3 + 2] - sR[j * 3 + 2];
      float u = 1.0f / sqrtf(dx * dx + dy * dy + dz * dz);
      ws[OFF_XS + m * NP + p] = u;
      acc += u * u;
    }
    for (int off = 32; off; off >>= 1) acc += __shfl_down(acc, off);
    if ((tid & 63) == 0) sAcc[tid >> 6] = acc;
    __syncthreads();
    if (tid == 0) ws[OFF_UU + m] = sAcc[0] + sAcc[1] + sAcc[2] + sAcc[3];
  } else {
    const int t = (blockIdx.x - MM) * 4 + (tid >> 6);
    const int lane = tid & 63;
    if (t < NT) {
      const float* vrow = xt + (size_t)t * NP;
      const float* jrow = Ja + (size_t)t * NP;
      float a = 0.f, b = 0.f;
      for (int p = lane; p < NP; p += 64) {
        float v = vrow[p], j = jrow[p];
        a += v * v;
        b += v * j;
      }
      for (int off = 32; off; off >>= 1) {
        a += __shfl_down(a, off);
        b += __shfl_down(b, off);
      }
      if (lane == 0) { ws[OFF_VV + t] = a; ws[OFF_C1 + t] = b; }
    }
  }
}

// ---------- kernel 2: fused GEMM1 + elementwise ----------
// tile 64m x 16t, block 128 (thread = 4m x 2t x 2mat), grid 375.
// B (xt,Ja interleaved) in LDS once; A (xs) from L1/L2: 4 INDEPENDENT float4
// loads per k-quad (hardware MLP). One barrier before loop, one after for the
// coalesced Es/sumw atomic gather.
#define G1_BS 278  // float2 stride per t-row
__global__ __launch_bounds__(128) void k_g1(const float* __restrict__ xt,
                                            const float* __restrict__ Ja,
                                            float* __restrict__ ws) {
  __shared__ __align__(16) float2 Bs[16][G1_BS];
  __shared__ float sEs[64], sSw[64];
  const int tid = threadIdx.x;
  const int t0 = blockIdx.x * 16;
  // stage B: 16 rows x 69 float4-quads per matrix
  for (int idx = tid; idx < 16 * 69; idx += 128) {
    const int row = idx / 69;
    const int k = (idx - row * 69) * 4;
    const float4 v = *(const float4*)(xt + (size_t)(t0 + row) * NP + k);
    const float4 j = *(const float4*)(Ja + (size_t)(t0 + row) * NP + k);
    *(float4*)&Bs[row][k]     = make_float4(v.x, j.x, v.y, j.y);
    *(float4*)&Bs[row][k + 2] = make_float4(v.z, j.z, v.w, j.w);
  }
  const int c = tid & 7;    // t-pair
  const int r = tid >> 3;   // m-quad 0..15 -> m = 4r..4r+3
  const float* __restrict__ ar0 = ws + OFF_XS + (4 * r + 0) * NP;
  const float* __restrict__ ar1 = ws + OFF_XS + (4 * r + 1) * NP;
  const float* __restrict__ ar2 = ws + OFF_XS + (4 * r + 2) * NP;
  const float* __restrict__ ar3 = ws + OFF_XS + (4 * r + 3) * NP;
  const float4 uu4 = *(const float4*)(ws + OFF_UU + 4 * r);
  const float2 vv2 = *(const float2*)(ws + OFF_VV + t0 + 2 * c);
  const float2 c12 = *(const float2*)(ws + OFF_C1 + t0 + 2 * c);
  __syncthreads();

  float accv[2][4] = {{0.f,0.f,0.f,0.f},{0.f,0.f,0.f,0.f}};
  float accj[2][4] = {{0.f,0.f,0.f,0.f},{0.f,0.f,0.f,0.f}};
#pragma unroll 3
  for (int q = 0; q < 69; q++) {
    const int k = 4 * q;
    float4 A[4];
    A[0] = *(const float4*)(ar0 + k);   // 4 independent global streams
    A[1] = *(const float4*)(ar1 + k);
    A[2] = *(const float4*)(ar2 + k);
    A[3] = *(const float4*)(ar3 + k);
    const float4 b00 = *(const float4*)&Bs[2 * c][k];        // (v,j) k,k+1
    const float4 b01 = *(const float4*)&Bs[2 * c][k + 2];    // (v,j) k+2,k+3
    const float4 b10 = *(const float4*)&Bs[2 * c + 1][k];
    const float4 b11 = *(const float4*)&Bs[2 * c + 1][k + 2];
#pragma unroll
    for (int i = 0; i < 4; i++) {
      const float4 a = A[i];
      accv[0][i] = fmaf(a.x, b00.x, accv[0][i]); accj[0][i] = fmaf(a.x, b00.y, accj[0][i]);
      accv[0][i] = fmaf(a.y, b00.z, accv[0][i]); accj[0][i] = fmaf(a.y, b00.w, accj[0][i]);
      accv[0][i] = fmaf(a.z, b01.x, accv[0][i]); accj[0][i] = fmaf(a.z, b01.y, accj[0][i]);
      accv[0][i] = fmaf(a.w, b01.z, accv[0][i]); accj[0][i] = fmaf(a.w, b01.w, accj[0][i]);
      accv[1][i] = fmaf(a.x, b10.x, accv[1][i]); accj[1][i] = fmaf(a.x, b10.y, accj[1][i]);
      accv[1][i] = fmaf(a.y, b10.z, accv[1][i]); accj[1][i] = fmaf(a.y, b10.w, accj[1][i]);
      accv[1][i] = fmaf(a.z, b11.x, accv[1][i]); accj[1][i] = fmaf(a.z, b11.y, accj[1][i]);
      accv[1][i] = fmaf(a.w, b11.z, accv[1][i]); accj[1][i] = fmaf(a.w, b11.w, accj[1][i]);
    }
  }

  // fused elementwise epilogue; per-thread t = t0+2c+tt, m = 4r+i
  float es_p[4] = {0.f,0.f,0.f,0.f}, sw_p[4] = {0.f,0.f,0.f,0.f};
  float wv[2][4], ev[2][4];
#pragma unroll
  for (int tt = 0; tt < 2; tt++) {
    const float vvt = tt ? vv2.y : vv2.x;
    const float c1t = tt ? c12.y : c12.x;
#pragma unroll
    for (int i = 0; i < 4; i++) {
      float d2 = fmaxf(f4c(uu4, i) - 2.f * accv[tt][i] + vvt, 0.f);
      float xd = QC * sqrtf(d2);
      float dv = QC * (accj[tt][i] - c1t);
      float ex = EXPC * __expf(-xd);
      float e1v = ex * (1.f + xd);
      float w_ = ex * dv;
      wv[tt][i] = w_; ev[tt][i] = e1v;
      es_p[i] += e1v * dv;
      sw_p[i] += w_;
    }
  }
#pragma unroll
  for (int tt = 0; tt < 2; tt++) {
    const int t = t0 + 2 * c + tt;
    *(float4*)(ws + OFF_WT + (size_t)t * 64 + 4 * r) =
        make_float4(wv[tt][0], wv[tt][1], wv[tt][2], wv[tt][3]);
    *(float4*)(ws + OFF_ET + (size_t)t * 64 + 4 * r) =
        make_float4(ev[tt][0], ev[tt][1], ev[tt][2], ev[tt][3]);
  }
  // reduce over the 8 c-lanes of each m, park in LDS, one coalesced atomic wave
#pragma unroll
  for (int off = 4; off; off >>= 1) {
#pragma unroll
    for (int i = 0; i < 4; i++) {
      es_p[i] += __shfl_down(es_p[i], off, 8);
      sw_p[i] += __shfl_down(sw_p[i], off, 8);
    }
  }
  if (c == 0) {
#pragma unroll
    for (int i = 0; i < 4; i++) { sEs[4 * r + i] = es_p[i]; sSw[4 * r + i] = sw_p[i]; }
  }
  __syncthreads();
  if (tid < 64) {
    atomicAdd(ws + OFF_ES + tid, sEs[tid]);
    atomicAdd(ws + OFF_SW + tid, sSw[tid]);
  }
}

// ---------- kernel 3: GEMM2 partials with 4 independent K-streams ----------
// grid (18 p-tiles x 47 k-chunks of 128); block 256: lane = m, wave-group = p.
// Per k: 2 coalesced b32 A-loads + 2 broadcast b128 LDS B-reads + 8 FMA;
// 4 interleaved streams of 32 k give 8 loads in flight. Shadow atomics.
#define G2_KC 128
__global__ __launch_bounds__(256) void k_g2(const float* __restrict__ xt,
                                            const float* __restrict__ Ja,
                                            float* __restrict__ ws) {
  __shared__ __align__(16) float Bsv[G2_KC][16];
  __shared__ __align__(16) float Bsj[G2_KC][16];
  const int tid = threadIdx.x;
  const int p0 = blockIdx.x * 16;
  const int k0 = blockIdx.y * G2_KC;
  const int validp = (NP - p0 < 16) ? (NP - p0) : 16;

  for (int idx = tid; idx < G2_KC * 8; idx += 256) {
    const int q = idx & 3;
    const int mat = (idx >> 2) & 1;
    const int row = idx >> 3;
    float4 val = make_float4(0.f, 0.f, 0.f, 0.f);
    if (q * 4 < validp && k0 + row < NT)
      val = *(const float4*)((mat ? Ja : xt) + (size_t)(k0 + row) * NP + p0 + q * 4);
    *(float4*)&(mat ? Bsj : Bsv)[row][q * 4] = val;
  }
  __syncthreads();

  const int m = tid & 63;
  const int pg = tid >> 6;  // 0..3
  const float* __restrict__ wtp = ws + OFF_WT + (size_t)k0 * 64 + m;
  const float* __restrict__ etp = ws + OFF_ET + (size_t)k0 * 64 + m;
  float acc1[4][4] = {{0}}, acc2[4][4] = {{0}};

#pragma unroll 2
  for (int i = 0; i < 32; i++) {
    float aw[4], ae[4];
#pragma unroll
    for (int s = 0; s < 4; s++) {       // 8 independent loads in flight
      const int k = 32 * s + i;
      aw[s] = wtp[k * 64];
      ae[s] = etp[k * 64];
    }
#pragma unroll
    for (int s = 0; s < 4; s++) {
      const int k = 32 * s + i;
      const float4 bv = *(const float4*)&Bsv[k][pg * 4];
      const float4 bj = *(const float4*)&Bsj[k][pg * 4];
      acc1[s][0] = fmaf(aw[s], bv.x, acc1[s][0]); acc2[s][0] = fmaf(ae[s], bj.x, acc2[s][0]);
      acc1[s][1] = fmaf(aw[s], bv.y, acc1[s][1]); acc2[s][1] = fmaf(ae[s], bj.y, acc2[s][1]);
      acc1[s][2] = fmaf(aw[s], bv.z, acc1[s][2]); acc2[s][2] = fmaf(ae[s], bj.z, acc2[s][2]);
      acc1[s][3] = fmaf(aw[s], bv.w, acc1[s][3]); acc2[s][3] = fmaf(ae[s], bj.w, acc2[s][3]);
    }
  }

  const int sh = blockIdx.y & 7;
  float* base1 = ws + OFF_SH + (size_t)(sh * 2 + 0) * NP * 64;
  float* base2 = ws + OFF_SH + (size_t)(sh * 2 + 1) * NP * 64;
#pragma unroll
  for (int j = 0; j < 4; j++) {
    const int p = p0 + pg * 4 + j;
    if (pg * 4 + j < validp) {
      const float v1 = acc1[0][j] + acc1[1][j] + acc1[2][j] + acc1[3][j];
      const float v2 = acc2[0][j] + acc2[1][j] + acc2[2][j] + acc2[3][j];
      atomicAdd(base1 + (size_t)p * 64 + m, v1);
      atomicAdd(base2 + (size_t)p * 64 + m, v2);
    }
  }
}

// ---------- kernel 4: finalize (reduce shadows, force gather, Es) ----------
__global__ __launch_bounds__(320) void k_final(const float* __restrict__ Rs,
                                               const float* __restrict__ ws,
                                               float* __restrict__ out) {
  const int m = blockIdx.x;
  const int tid = threadIdx.x;
  __shared__ float fx[NP];
  __shared__ float sR[NA * 3];
  if (tid < NA * 3) sR[tid] = Rs[m * NA * 3 + tid];
  const float sw = ws[OFF_SW + m];
  for (int p = tid; p < NP; p += 320) {
    float f1p = 0.f, f2 = 0.f;
#pragma unroll
    for (int s = 0; s < 8; s++) {
      f1p += ws[OFF_SH + ((size_t)(s * 2 + 0) * NP + p) * 64 + m];
      f2  += ws[OFF_SH + ((size_t)(s * 2 + 1) * NP + p) * 64 + m];
    }
    const float u = ws[OFF_XS + m * NP + p];
    const float F1 = QC * (u * sw - f1p);
    fx[p] = (F1 - f2) * u * u * u;
  }
  __syncthreads();
  if (tid == 0) out[m] = ws[OFF_ES + m] / QC;  // *STD + C, STD=1, C=0
  if (tid < NA * 3) {
    const int a = tid / 3, cc = tid % 3;
    const float ra = sR[a * 3 + cc];
    float acc = 0.f;
    for (int b = 0; b < NA; b++) {
      if (b == a) continue;
      const int i = a > b ? a : b, j = a > b ? b : a;
      const int p = i * (i - 1) / 2 + j;
      acc += (sR[b * 3 + cc] - ra) * fx[p];
    }
    out[MM + m * NA * 3 + tid] = acc;
  }
}

extern "C" void kernel_launch(void* const* d_in, const int* in_sizes, int n_in,
                              void* d_out, int out_size, void* d_ws, size_t ws_size,
                              hipStream_t stream) {
  const float* Rs = (const float*)d_in[0];
  const float* xt = (const float*)d_in[1];
  const float* Ja = (const float*)d_in[2];
  float* out = (float*)d_out;
  float* ws = (float*)d_ws;

  k_pre<<<MM + NT / 4, 256, 0, stream>>>(Rs, xt, Ja, ws);
  k_g1<<<NT / 16, 128, 0, stream>>>(xt, Ja, ws);
  k_g2<<<dim3(18, 47), 256, 0, stream>>>(xt, Ja, ws);
  k_final<<<MM, 320, 0, stream>>>(Rs, ws, out);
}

// Round 8
// 136.201 us; speedup vs baseline: 1.2888x; 1.0615x over previous
//
#include <hip/hip_runtime.h>
#include <math.h>

#define MM 64
#define NA 24
#define NP 276
#define NT 6000
#define NTP 6048   // wT/eT rows padded to 63*96 (tail zeroed)
#define QC 0.22360679774997896f
#define EXPC 0.01666666666666667f  // 5/(3*sig^2), sig=10

// ws layout (float offsets)
#define OFF_XST  0        // xsT[p][m] 276*64
#define OFF_UU   17664    // 64
#define OFF_ES   17728    // 64  (zeroed)
#define OFF_SW   17792    // 64  (zeroed)
#define OFF_SH   17856    // 16 shadow arrays [276][64] (zeroed): idx (sh*2+mat)
#define OFF_WT   300480   // wT[t][m] NTP*64
#define OFF_ET   687552   // eT[t][m] NTP*64
#define ZTOT     282752   // ES+SW+SH

__device__ __forceinline__ float f4c(const float4& v, int i) {
  return i == 0 ? v.x : i == 1 ? v.y : i == 2 ? v.z : v.w;
}

// ---------- kernel 1: zero accum + tails; xsT[p][m] + uu ----------
__global__ __launch_bounds__(256) void k_pre(const float* __restrict__ Rs,
                                             float* __restrict__ ws) {
  const int tid = threadIdx.x;
  for (int z = blockIdx.x * 256 + tid; z < ZTOT; z += gridDim.x * 256)
    ws[OFF_ES + z] = 0.f;
  for (int z = blockIdx.x * 256 + tid; z < 6144; z += gridDim.x * 256) {
    if (z < 3072) ws[OFF_WT + 384000 + z] = 0.f;
    else          ws[OFF_ET + 384000 + (z - 3072)] = 0.f;
  }
  if (blockIdx.x < MM) {
    const int m = blockIdx.x;
    __shared__ float sR[NA * 3];
    __shared__ float sAcc[4];
    if (tid < NA * 3) sR[tid] = Rs[m * NA * 3 + tid];
    __syncthreads();
    float acc = 0.f;
    for (int p = tid; p < NP; p += 256) {
      int i = (int)((1.0f + sqrtf(1.0f + 8.0f * (float)p)) * 0.5f);
      while (i * (i - 1) / 2 > p) i--;
      while ((i + 1) * i / 2 <= p) i++;
      int j = p - i * (i - 1) / 2;
      float dx = sR[i * 3 + 0] - sR[j * 3 + 0];
      float dy = sR[i * 3 + 1] - sR[j * 3 + 1];
      float dz = sR[i * 3 + 2] - sR[j * 3 + 2];
      float u = 1.0f / sqrtf(dx * dx + dy * dy + dz * dz);
      ws[OFF_XST + p * 64 + m] = u;
      acc += u * u;
    }
    for (int off = 32; off; off >>= 1) acc += __shfl_down(acc, off);
    if ((tid & 63) == 0) sAcc[tid >> 6] = acc;
    __syncthreads();
    if (tid == 0) ws[OFF_UU + m] = sAcc[0] + sAcc[1] + sAcc[2] + sAcc[3];
  }
}

// ---------- kernel 2: fused GEMM1 + stats + elementwise, all-LDS hot loop ----------
// grid (375 t-tiles, 2 m-halves); block 256 = tile 32m x 16t.
// Thread: r = tid&15 -> m-pair (m0+2r, +1); c = tid>>4 -> t = t0+c.
// LDS: Bs[t][k] = (xt, Ja) interleaved; As[p][m-local] (xs half, transposed).
// Stats (vv, c1) computed in-block from staged Bs.
#define G1_BS 280  // float2 per t-row
#define G1_AS 36   // As row stride (floats), mult of 4
__global__ __launch_bounds__(256, 2) void k_g1(const float* __restrict__ xt,
                                               const float* __restrict__ Ja,
                                               float* __restrict__ ws) {
  __shared__ __align__(16) float2 Bs[16][G1_BS];
  __shared__ __align__(16) float As[NP][G1_AS];
  __shared__ float sVV[16], sC1[16];
  __shared__ float sEsW[4][32], sSwW[4][32];
  const int tid = threadIdx.x;
  const int t0 = blockIdx.x * 16;
  const int m0 = blockIdx.y * 32;

  // stage B: 16 t-rows x 69 float4-quads of xt & Ja, interleaved (v,j)
  for (int idx = tid; idx < 16 * 69; idx += 256) {
    const int row = idx / 69;
    const int kq = (idx - row * 69) * 4;
    const float4 v = *(const float4*)(xt + (size_t)(t0 + row) * NP + kq);
    const float4 j = *(const float4*)(Ja + (size_t)(t0 + row) * NP + kq);
    *(float4*)&Bs[row][kq]     = make_float4(v.x, j.x, v.y, j.y);
    *(float4*)&Bs[row][kq + 2] = make_float4(v.z, j.z, v.w, j.w);
  }
  // stage A: 276 p-rows x 8 m-quads from xsT (L2-hot)
  for (int idx = tid; idx < NP * 8; idx += 256) {
    const int p = idx >> 3;
    const int mq = (idx & 7) * 4;
    *(float4*)&As[p][mq] = *(const float4*)(ws + OFF_XST + p * 64 + m0 + mq);
  }
  const int r = tid & 15;   // m-pair
  const int c = tid >> 4;   // t-column
  const float2 uu2 = *(const float2*)(ws + OFF_UU + m0 + 2 * r);
  __syncthreads();

  // in-block stats: vv[t], c1[t] from staged Bs
  {
    const int tl = tid >> 4;
    const int l16 = tid & 15;
    float a = 0.f, b = 0.f;
    for (int k = l16; k < NP; k += 16) {
      const float2 x = Bs[tl][k];
      a = fmaf(x.x, x.x, a);
      b = fmaf(x.x, x.y, b);
    }
#pragma unroll
    for (int off = 8; off; off >>= 1) {
      a += __shfl_down(a, off, 16);
      b += __shfl_down(b, off, 16);
    }
    if (l16 == 0) { sVV[tl] = a; sC1[tl] = b; }
  }
  __syncthreads();

  float av0 = 0.f, av1 = 0.f, aj0 = 0.f, aj1 = 0.f;
#pragma unroll 4
  for (int kk = 0; kk < NP; kk += 2) {
    const float4 b  = *(const float4*)&Bs[c][kk];    // (v_k, j_k, v_k1, j_k1)
    const float2 a0 = *(const float2*)&As[kk][2 * r];
    const float2 a1 = *(const float2*)&As[kk + 1][2 * r];
    av0 = fmaf(a0.x, b.x, av0); aj0 = fmaf(a0.x, b.y, aj0);
    av1 = fmaf(a0.y, b.x, av1); aj1 = fmaf(a0.y, b.y, aj1);
    av0 = fmaf(a1.x, b.z, av0); aj0 = fmaf(a1.x, b.w, aj0);
    av1 = fmaf(a1.y, b.z, av1); aj1 = fmaf(a1.y, b.w, aj1);
  }

  // elementwise epilogue: t = t0+c, m = m0+2r+{0,1}
  const float vvt = sVV[c];
  const float c1t = sC1[c];
  float es2[2], sw2[2], wv[2], ev[2];
#pragma unroll
  for (int i = 0; i < 2; i++) {
    const float g1v = i ? av1 : av0;
    const float g2v = i ? aj1 : aj0;
    const float uum = i ? uu2.y : uu2.x;
    float d2 = fmaxf(uum - 2.f * g1v + vvt, 0.f);
    float xd = QC * sqrtf(d2);
    float dv = QC * (g2v - c1t);
    float ex = EXPC * __expf(-xd);
    float e1v = ex * (1.f + xd);
    float w_ = ex * dv;
    wv[i] = w_; ev[i] = e1v;
    es2[i] = e1v * dv;
    sw2[i] = w_;
  }
  const int t = t0 + c;
  *(float2*)(ws + OFF_WT + (size_t)t * 64 + m0 + 2 * r) = make_float2(wv[0], wv[1]);
  *(float2*)(ws + OFF_ET + (size_t)t * 64 + m0 + 2 * r) = make_float2(ev[0], ev[1]);

  // reduce es/sw over the wave's 4 c-groups, park per wave, then coalesced atomics
#pragma unroll
  for (int i = 0; i < 2; i++) {
    es2[i] += __shfl_down(es2[i], 32); es2[i] += __shfl_down(es2[i], 16);
    sw2[i] += __shfl_down(sw2[i], 32); sw2[i] += __shfl_down(sw2[i], 16);
  }
  const int w = tid >> 6;
  if ((tid & 63) < 16) {
    sEsW[w][2 * r + 0] = es2[0]; sEsW[w][2 * r + 1] = es2[1];
    sSwW[w][2 * r + 0] = sw2[0]; sSwW[w][2 * r + 1] = sw2[1];
  }
  __syncthreads();
  if (tid < 32) {
    const float es = sEsW[0][tid] + sEsW[1][tid] + sEsW[2][tid] + sEsW[3][tid];
    const float sw = sSwW[0][tid] + sSwW[1][tid] + sSwW[2][tid] + sSwW[3][tid];
    atomicAdd(ws + OFF_ES + m0 + tid, es);
    atomicAdd(ws + OFF_SW + m0 + tid, sw);
  }
}

// ---------- kernel 3: GEMM2 partials, all-LDS hot loop, shadow atomics ----------
// grid (18 p-tiles x 63 k-chunks of 96); block 256 = tile 64m x 16p.
// Thread: r = tid&31 -> m-pair (2r, 2r+1); c = tid>>5 -> p-pair (p0+2c, +1).
#define G2_KC 96
#define G2_AS 68   // Aw/Ae row stride
#define G2_BS 18   // Bvj row stride (float2)
__global__ __launch_bounds__(256, 2) void k_g2(const float* __restrict__ xt,
                                               const float* __restrict__ Ja,
                                               float* __restrict__ ws) {
  __shared__ __align__(16) float Aw[G2_KC][G2_AS];
  __shared__ __align__(16) float Ae[G2_KC][G2_AS];
  __shared__ __align__(16) float2 Bvj[G2_KC][G2_BS];
  const int tid = threadIdx.x;
  const int p0 = blockIdx.x * 16;
  const int k0 = blockIdx.y * G2_KC;
  const int validp = (NP - p0 < 16) ? (NP - p0) : 16;

  // stage A: wT/eT rows k0..k0+95 (rows >= NT are zero-padded in ws)
  for (int idx = tid; idx < G2_KC * 16; idx += 256) {
    const int k = idx >> 4;
    const int mq = (idx & 15) * 4;
    *(float4*)&Aw[k][mq] = *(const float4*)(ws + OFF_WT + (size_t)(k0 + k) * 64 + mq);
    *(float4*)&Ae[k][mq] = *(const float4*)(ws + OFF_ET + (size_t)(k0 + k) * 64 + mq);
  }
  // stage B: (xt,Ja) interleaved [k][p-local]
  for (int idx = tid; idx < G2_KC * 4; idx += 256) {
    const int k = idx >> 2;
    const int pq = (idx & 3) * 4;
    const int t = k0 + k;
    float4 v = make_float4(0.f, 0.f, 0.f, 0.f), j = v;
    if (pq < validp && t < NT) {
      v = *(const float4*)(xt + (size_t)t * NP + p0 + pq);
      j = *(const float4*)(Ja + (size_t)t * NP + p0 + pq);
    }
    *(float4*)&Bvj[k][pq]     = make_float4(v.x, j.x, v.y, j.y);
    *(float4*)&Bvj[k][pq + 2] = make_float4(v.z, j.z, v.w, j.w);
  }
  __syncthreads();

  const int r = tid & 31;   // m-pair
  const int c = tid >> 5;   // p-pair
  float f1[2][2] = {{0.f, 0.f}, {0.f, 0.f}};  // [m][p]
  float f2[2][2] = {{0.f, 0.f}, {0.f, 0.f}};
#pragma unroll 4
  for (int k = 0; k < G2_KC; k++) {
    const float2 aw = *(const float2*)&Aw[k][2 * r];
    const float2 ae = *(const float2*)&Ae[k][2 * r];
    const float4 b  = *(const float4*)&Bvj[k][2 * c];  // (v_p, j_p, v_p1, j_p1)
    f1[0][0] = fmaf(aw.x, b.x, f1[0][0]); f1[0][1] = fmaf(aw.x, b.z, f1[0][1]);
    f1[1][0] = fmaf(aw.y, b.x, f1[1][0]); f1[1][1] = fmaf(aw.y, b.z, f1[1][1]);
    f2[0][0] = fmaf(ae.x, b.y, f2[0][0]); f2[0][1] = fmaf(ae.x, b.w, f2[0][1]);
    f2[1][0] = fmaf(ae.y, b.y, f2[1][0]); f2[1][1] = fmaf(ae.y, b.w, f2[1][1]);
  }

  const int sh = blockIdx.y & 7;
  float* b1 = ws + OFF_SH + (size_t)(sh * 2 + 0) * NP * 64;
  float* b2 = ws + OFF_SH + (size_t)(sh * 2 + 1) * NP * 64;
#pragma unroll
  for (int j = 0; j < 2; j++) {
    const int pl = 2 * c + j;
    if (pl < validp) {
      const int p = p0 + pl;
#pragma unroll
      for (int i = 0; i < 2; i++) {
        atomicAdd(b1 + (size_t)p * 64 + 2 * r + i, f1[i][j]);
        atomicAdd(b2 + (size_t)p * 64 + 2 * r + i, f2[i][j]);
      }
    }
  }
}

// ---------- kernel 4: finalize (reduce shadows, force gather, Es) ----------
__global__ __launch_bounds__(320) void k_final(const float* __restrict__ Rs,
                                               const float* __restrict__ ws,
                                               float* __restrict__ out) {
  const int m = blockIdx.x;
  const int tid = threadIdx.x;
  __shared__ float fx[NP];
  __shared__ float sR[NA * 3];
  if (tid < NA * 3) sR[tid] = Rs[m * NA * 3 + tid];
  const float sw = ws[OFF_SW + m];
  for (int p = tid; p < NP; p += 320) {
    float f1p = 0.f, f2 = 0.f;
#pragma unroll
    for (int s = 0; s < 8; s++) {
      f1p += ws[OFF_SH + ((size_t)(s * 2 + 0) * NP + p) * 64 + m];
      f2  += ws[OFF_SH + ((size_t)(s * 2 + 1) * NP + p) * 64 + m];
    }
    const float u = ws[OFF_XST + p * 64 + m];
    const float F1 = QC * (u * sw - f1p);
    fx[p] = (F1 - f2) * u * u * u;
  }
  __syncthreads();
  if (tid == 0) out[m] = ws[OFF_ES + m] / QC;  // *STD + C, STD=1, C=0
  if (tid < NA * 3) {
    const int a = tid / 3, cc = tid % 3;
    const float ra = sR[a * 3 + cc];
    float acc = 0.f;
    for (int b = 0; b < NA; b++) {
      if (b == a) continue;
      const int i = a > b ? a : b, j = a > b ? b : a;
      const int p = i * (i - 1) / 2 + j;
      acc += (sR[b * 3 + cc] - ra) * fx[p];
    }
    out[MM + m * NA * 3 + tid] = acc;
  }
}

extern "C" void kernel_launch(void* const* d_in, const int* in_sizes, int n_in,
                              void* d_out, int out_size, void* d_ws, size_t ws_size,
                              hipStream_t stream) {
  const float* Rs = (const float*)d_in[0];
  const float* xt = (const float*)d_in[1];
  const float* Ja = (const float*)d_in[2];
  float* out = (float*)d_out;
  float* ws = (float*)d_ws;

  k_pre<<<256, 256, 0, stream>>>(Rs, ws);
  k_g1<<<dim3(375, 2), 256, 0, stream>>>(xt, Ja, ws);
  k_g2<<<dim3(18, 63), 256, 0, stream>>>(xt, Ja, ws);
  k_final<<<MM, 320, 0, stream>>>(Rs, ws, out);
}